// Round 6
// baseline (586.954 us; speedup 1.0000x reference)
//
#include <hip/hip_runtime.h>
#include <cstdint>
#include <cstddef>

typedef __bf16 bf16x8 __attribute__((ext_vector_type(8)));
typedef __bf16 bf16x4 __attribute__((ext_vector_type(4)));
typedef float f32x4 __attribute__((ext_vector_type(4)));
typedef unsigned short u16x4 __attribute__((ext_vector_type(4)));
typedef short s16x4 __attribute__((ext_vector_type(4)));

// fp32 -> bf16 round-to-nearest-even
__device__ __forceinline__ unsigned short f2bf(float f) {
  union { float f; unsigned u; } v; v.f = f;
  unsigned r = (v.u + 0x7FFF + ((v.u >> 16) & 1)) >> 16;
  return (unsigned short)r;
}

// async global->LDS, 16B per lane
__device__ __forceinline__ void gl2lds16(const void* g, void* l) {
  __builtin_amdgcn_global_load_lds(
      (const __attribute__((address_space(1))) void*)g,
      (__attribute__((address_space(3))) void*)l,
      16, 0, 0);
}

// ---------------------------------------------------------------- prep
__global__ __launch_bounds__(256) void cast_f32_bf16(
    const float* __restrict__ in, unsigned short* __restrict__ out, int n) {
  int i = (blockIdx.x * 256 + threadIdx.x) * 4;
  if (i >= n) return;
  float4 v = *(const float4*)(in + i);
  u16x4 o;
  o[0] = f2bf(v.x); o[1] = f2bf(v.y); o[2] = f2bf(v.z); o[3] = f2bf(v.w);
  *(u16x4*)(out + i) = o;
}

__global__ __launch_bounds__(256) void transpose_cast(
    const float* __restrict__ in, unsigned short* __restrict__ out, int R, int C) {
  __shared__ float t[32][33];
  int c0 = blockIdx.x * 32, r0 = blockIdx.y * 32;
  int tx = threadIdx.x, ty = threadIdx.y;
#pragma unroll
  for (int j = 0; j < 4; ++j)
    t[ty + j * 8][tx] = in[(size_t)(r0 + ty + j * 8) * C + c0 + tx];
  __syncthreads();
#pragma unroll
  for (int j = 0; j < 4; ++j)
    out[(size_t)(c0 + ty + j * 8) * R + r0 + tx] = f2bf(t[tx][ty + j * 8]);
}

// key_padding_mask -> additive float; per-batch max unpadded key index+1.
// Wave-level max reduce first: 1 atomic per wave (not per thread).
__global__ __launch_bounds__(256) void prep_pad(
    const int* __restrict__ mask, float* __restrict__ padd, int* __restrict__ kmax, int n) {
  int i = blockIdx.x * 256 + threadIdx.x;
  if (i >= n) return;
  int mv = mask[i];
  padd[i] = mv ? -1e30f : 0.0f;
  int key = mv ? 0 : ((i & 2047) + 1);
#pragma unroll
  for (int off = 32; off; off >>= 1) key = max(key, __shfl_xor(key, off, 64));
  if ((threadIdx.x & 63) == 0) atomicMax(&kmax[i >> 11], key);  // i>>11 wave-uniform
}

// ---------------------------------------------------------------- GEMM (C = A[M,K] * B[N,K]^T)
template <int EPI>
__global__ __launch_bounds__(256) void gemm_bt(
    const unsigned short* __restrict__ A, const unsigned short* __restrict__ Bm,
    const float* __restrict__ bias, float* __restrict__ outF,
    unsigned short* __restrict__ Qb, unsigned short* __restrict__ Kb,
    unsigned short* __restrict__ Vt, int M, int N, int K) {
  __shared__ unsigned short As[128 * 32];
  __shared__ unsigned short Bs[128 * 32];
  const int tid = threadIdx.x;
  const int bm = blockIdx.x * 128;
  const int bn = blockIdx.y * 128;
  const int wave = tid >> 6, lane = tid & 63;
  const int wm = (wave >> 1) * 64, wn = (wave & 1) * 64;
  const int lr = lane & 15, lq = lane >> 4;

  f32x4 acc[4][4] = {};

  const int c0 = tid, c1 = tid + 256;
  const int rA0 = c0 >> 2, colA0 = (c0 & 3) * 8;
  const int rA1 = c1 >> 2, colA1 = (c1 & 3) * 8;

  for (int k0 = 0; k0 < K; k0 += 32) {
    __syncthreads();
    gl2lds16(A + (size_t)(bm + rA0) * K + k0 + colA0, As + c0 * 8);
    gl2lds16(A + (size_t)(bm + rA1) * K + k0 + colA1, As + c1 * 8);
    gl2lds16(Bm + (size_t)(bn + rA0) * K + k0 + colA0, Bs + c0 * 8);
    gl2lds16(Bm + (size_t)(bn + rA1) * K + k0 + colA1, Bs + c1 * 8);
    __syncthreads();
    bf16x8 af[4], bfr[4];
#pragma unroll
    for (int mi = 0; mi < 4; ++mi)
      af[mi] = *(const bf16x8*)(As + (wm + mi * 16 + lr) * 32 + lq * 8);
#pragma unroll
    for (int nj = 0; nj < 4; ++nj)
      bfr[nj] = *(const bf16x8*)(Bs + (wn + nj * 16 + lr) * 32 + lq * 8);
#pragma unroll
    for (int mi = 0; mi < 4; ++mi)
#pragma unroll
      for (int nj = 0; nj < 4; ++nj)
        acc[mi][nj] = __builtin_amdgcn_mfma_f32_16x16x32_bf16(af[mi], bfr[nj], acc[mi][nj], 0, 0, 0);
  }

#pragma unroll
  for (int mi = 0; mi < 4; ++mi) {
#pragma unroll
    for (int nj = 0; nj < 4; ++nj) {
#pragma unroll
      for (int r = 0; r < 4; ++r) {
        int m = bm + wm + mi * 16 + lq * 4 + r;
        int n = bn + wn + nj * 16 + lr;
        float v = acc[mi][nj][r] + bias[n];
        if (EPI == 0) {
          int b = m >> 11, t = m & 2047;
          int part = n >> 10, d = n & 1023;
          int h = d >> 6, hd = d & 63;
          size_t qk = ((size_t)(b * 16 + h) * 2048 + t) * 64 + hd;
          // fold softmax scale 1/sqrt(64) and log2(e) into Q
          if (part == 0)      Qb[qk] = f2bf(v * 0.18033688011112042f);
          else if (part == 1) Kb[qk] = f2bf(v);
          else                Vt[((size_t)(b * 16 + h) * 64 + hd) * 2048 + t] = f2bf(v);
        } else {
          outF[(size_t)m * N + n] = v;
        }
      }
    }
  }
}

// ---------------------------------------------------------------- flash attention
// S^T = K Q^T: C-layout (key=4*lq+r, query=lr) is directly the A-operand of
// mfma_16x16x16bf16_1k for PV — no LDS, no barriers.
// 16 q-rows per wave, 128-key chunks (halves softmax merges per key vs 64).
// 4096 waves total (4/SIMD, all resident at VGPR<=128); uniform length via
// pairing tile pp with 127-pp. 4 waves/block share one (b,h) K/V stream.

__device__ __forceinline__ void process_tile16(
    const unsigned short* __restrict__ Qh, const unsigned short* __restrict__ Kh,
    const unsigned short* __restrict__ Vh, const float* __restrict__ pb,
    unsigned short* __restrict__ ctxBase, int q0, int kcapR,
    int lr, int lq, int bsrc) {
  bf16x8 qf0, qf1;
  {
    const unsigned short* qp = Qh + (size_t)(q0 + lr) * 64 + lq * 8;
    qf0 = *(const bf16x8*)(qp);
    qf1 = *(const bf16x8*)(qp + 32);
  }
  f32x4 O[4] = {};
  float m = -1e30f, l = 0.f;
  const bool diag = (q0 < kcapR);
  const int last = diag ? (q0 >> 7) : ((kcapR >> 7) - 1);

  for (int i = 0; i <= last; ++i) {
    const int kc = i << 7;
    f32x4 S[8];
    // QK^T over 128 keys (8 key-tiles of 16)
#pragma unroll
    for (int t = 0; t < 8; ++t) {
      const unsigned short* kp = Kh + (size_t)(kc + t * 16 + lr) * 64 + lq * 8;
      bf16x8 kf0 = *(const bf16x8*)(kp);
      bf16x8 kf1 = *(const bf16x8*)(kp + 32);
      f32x4 s = {};
      s = __builtin_amdgcn_mfma_f32_16x16x32_bf16(kf0, qf0, s, 0, 0, 0);
      s = __builtin_amdgcn_mfma_f32_16x16x32_bf16(kf1, qf1, s, 0, 0, 0);
      S[t] = s;
    }
    // padding addend
#pragma unroll
    for (int t = 0; t < 8; ++t) {
      float4 pd = *(const float4*)(pb + kc + t * 16 + 4 * lq);
      S[t][0] += pd.x; S[t][1] += pd.y; S[t][2] += pd.z; S[t][3] += pd.w;
    }
    if (diag && i == last) {
      const int q = q0 + lr;
#pragma unroll
      for (int t = 0; t < 8; ++t)
#pragma unroll
        for (int r = 0; r < 4; ++r) {
          int key = kc + t * 16 + 4 * lq + r;
          if (key > q) S[t][r] = -1e30f;
        }
    }
    // online softmax over the 128-key chunk (row = query = lr)
    float mx = -1e30f;
#pragma unroll
    for (int t = 0; t < 8; ++t)
#pragma unroll
      for (int r = 0; r < 4; ++r) mx = fmaxf(mx, S[t][r]);
    mx = fmaxf(mx, __shfl_xor(mx, 16, 64));
    mx = fmaxf(mx, __shfl_xor(mx, 32, 64));
    float mnew = fmaxf(m, mx);
    float al = __builtin_amdgcn_exp2f(m - mnew);
    m = mnew;
    float rs = 0.f;
#pragma unroll
    for (int t = 0; t < 8; ++t)
#pragma unroll
      for (int r = 0; r < 4; ++r) {
        float p = __builtin_amdgcn_exp2f(S[t][r] - mnew);
        S[t][r] = p;
        rs += p;
      }
    rs += __shfl_xor(rs, 16, 64);
    rs += __shfl_xor(rs, 32, 64);
    l = l * al + rs;
    // alpha: query=lr domain -> query=4*lq+r domain; rescale O
#pragma unroll
    for (int r = 0; r < 4; ++r) {
      float a = __shfl(al, bsrc + r, 64);
#pragma unroll
      for (int nj = 0; nj < 4; ++nj) O[nj][r] *= a;
    }
    // P cvt to bf16 A-frags (m=query=lr, k=key=4*lq+j)
    s16x4 pf[8];
#pragma unroll
    for (int t = 0; t < 8; ++t) {
      bf16x4 p4;
#pragma unroll
      for (int r = 0; r < 4; ++r) p4[r] = (__bf16)S[t][r];
      pf[t] = __builtin_bit_cast(s16x4, p4);
    }
    // PV: O[query=4*lq+r][hd=lr+nj*16]
#pragma unroll
    for (int nj = 0; nj < 4; ++nj) {
      const unsigned short* vp = Vh + (size_t)(nj * 16 + lr) * 2048 + kc + 4 * lq;
#pragma unroll
      for (int t = 0; t < 8; ++t) {
        s16x4 vf = *(const s16x4*)(vp + t * 16);
        O[nj] = __builtin_amdgcn_mfma_f32_16x16x16bf16_1k(pf[t], vf, O[nj], 0, 0, 0);
      }
    }
  }

  float linv = 1.0f / l;
#pragma unroll
  for (int r = 0; r < 4; ++r) {
    float li = __shfl(linv, bsrc + r, 64);
    int q = q0 + 4 * lq + r;
    unsigned short* cp = ctxBase + (size_t)q * 1024 + lr;
#pragma unroll
    for (int nj = 0; nj < 4; ++nj) cp[nj * 16] = f2bf(O[nj][r] * li);
  }
}

__global__ __launch_bounds__(256, 4) void flash_attn(
    const unsigned short* __restrict__ Qb, const unsigned short* __restrict__ Kb,
    const unsigned short* __restrict__ Vt, const float* __restrict__ padd,
    const int* __restrict__ kmax, unsigned short* __restrict__ ctx) {
  const int bid = blockIdx.x;      // 1024 blocks
  const int pg = bid >> 6;         // 0..15
  const int bh = bid & 63;
  const int b = bh >> 4, h = bh & 15;
  const int wave = threadIdx.x >> 6, lane = threadIdx.x & 63;
  const int lr = lane & 15, lq = lane >> 4;
  const int bsrc = 20 * lq;        // lane with lr == 4*lq+r
  const int pp = pg * 4 + wave;    // 0..63: pair (127-pp, pp)

  const unsigned short* Qh = Qb + (size_t)bh * 2048 * 64;
  const unsigned short* Kh = Kb + (size_t)bh * 2048 * 64;
  const unsigned short* Vh = Vt + (size_t)bh * 64 * 2048;
  const float* pb = padd + b * 2048;
  unsigned short* ctxBase = ctx + ((size_t)b * 2048) * 1024 + h * 64;
  const int kcapR = (kmax[b] + 127) & ~127;

  process_tile16(Qh, Kh, Vh, pb, ctxBase, (127 - pp) * 16, kcapR, lr, lq, bsrc);
  process_tile16(Qh, Kh, Vh, pb, ctxBase, pp * 16, kcapR, lr, lq, bsrc);
}

// ---------------------------------------------------------------- launch
extern "C" void kernel_launch(void* const* d_in, const int* in_sizes, int n_in,
                              void* d_out, int out_size, void* d_ws, size_t ws_size,
                              hipStream_t stream) {
  const float* x    = (const float*)d_in[0];
  const float* Wqkv = (const float*)d_in[1];
  const float* bqkv = (const float*)d_in[2];
  const float* Wo   = (const float*)d_in[3];
  const float* bo   = (const float*)d_in[4];
  const int*   mask = (const int*)d_in[5];
  float* out = (float*)d_out;

  unsigned short* ws = (unsigned short*)d_ws;
  const size_t SZ_X = (size_t)8192 * 1024;  // B*T*D
  unsigned short* xb    = ws;                                   // 16 MB, reused as ctx
  unsigned short* WqkvT = xb + SZ_X;                            // 6 MB
  unsigned short* WoT   = WqkvT + (size_t)3072 * 1024;          // 2 MB
  unsigned short* Qb    = WoT + (size_t)1024 * 1024;            // 16 MB
  unsigned short* Kb    = Qb + SZ_X;                            // 16 MB
  unsigned short* Vt    = Kb + SZ_X;                            // 16 MB
  float*          padd  = (float*)(Vt + SZ_X);                  // 32 KB
  int*            kmax  = (int*)(padd + 8192);                  // 16 B
  unsigned short* ctx   = xb;  // xb dead after GEMM1

  hipMemsetAsync(kmax, 0, 4 * sizeof(int), stream);
  cast_f32_bf16<<<8192, 256, 0, stream>>>(x, xb, (int)SZ_X);
  transpose_cast<<<dim3(96, 32), dim3(32, 8), 0, stream>>>(Wqkv, WqkvT, 1024, 3072);
  transpose_cast<<<dim3(32, 32), dim3(32, 8), 0, stream>>>(Wo, WoT, 1024, 1024);
  prep_pad<<<32, 256, 0, stream>>>(mask, padd, kmax, 8192);
  gemm_bt<0><<<dim3(64, 24), 256, 0, stream>>>(xb, WqkvT, bqkv, nullptr, Qb, Kb, Vt,
                                               8192, 3072, 1024);
  flash_attn<<<1024, 256, 0, stream>>>(Qb, Kb, Vt, padd, kmax, ctx);
  gemm_bt<1><<<dim3(64, 8), 256, 0, stream>>>(ctx, WoT, bo, out, nullptr, nullptr, nullptr,
                                              8192, 1024, 1024);
}

// Round 7
// 405.450 us; speedup vs baseline: 1.4477x; 1.4477x over previous
//
#include <hip/hip_runtime.h>
#include <cstdint>
#include <cstddef>

typedef __bf16 bf16x8 __attribute__((ext_vector_type(8)));
typedef __bf16 bf16x4 __attribute__((ext_vector_type(4)));
typedef float f32x4 __attribute__((ext_vector_type(4)));
typedef unsigned short u16x4 __attribute__((ext_vector_type(4)));
typedef short s16x4 __attribute__((ext_vector_type(4)));

// fp32 -> bf16 round-to-nearest-even
__device__ __forceinline__ unsigned short f2bf(float f) {
  union { float f; unsigned u; } v; v.f = f;
  unsigned r = (v.u + 0x7FFF + ((v.u >> 16) & 1)) >> 16;
  return (unsigned short)r;
}

// async global->LDS, 16B per lane
__device__ __forceinline__ void gl2lds16(const void* g, void* l) {
  __builtin_amdgcn_global_load_lds(
      (const __attribute__((address_space(1))) void*)g,
      (__attribute__((address_space(3))) void*)l,
      16, 0, 0);
}

// ---------------------------------------------------------------- prep
__global__ __launch_bounds__(256) void cast_f32_bf16(
    const float* __restrict__ in, unsigned short* __restrict__ out, int n) {
  int i = (blockIdx.x * 256 + threadIdx.x) * 4;
  if (i >= n) return;
  float4 v = *(const float4*)(in + i);
  u16x4 o;
  o[0] = f2bf(v.x); o[1] = f2bf(v.y); o[2] = f2bf(v.z); o[3] = f2bf(v.w);
  *(u16x4*)(out + i) = o;
}

__global__ __launch_bounds__(256) void transpose_cast(
    const float* __restrict__ in, unsigned short* __restrict__ out, int R, int C) {
  __shared__ float t[32][33];
  int c0 = blockIdx.x * 32, r0 = blockIdx.y * 32;
  int tx = threadIdx.x, ty = threadIdx.y;
#pragma unroll
  for (int j = 0; j < 4; ++j)
    t[ty + j * 8][tx] = in[(size_t)(r0 + ty + j * 8) * C + c0 + tx];
  __syncthreads();
#pragma unroll
  for (int j = 0; j < 4; ++j)
    out[(size_t)(c0 + ty + j * 8) * R + r0 + tx] = f2bf(t[tx][ty + j * 8]);
}

// key_padding_mask -> additive float; per-batch max unpadded key index+1.
// Wave-level max reduce first: 1 atomic per wave (not per thread).
__global__ __launch_bounds__(256) void prep_pad(
    const int* __restrict__ mask, float* __restrict__ padd, int* __restrict__ kmax, int n) {
  int i = blockIdx.x * 256 + threadIdx.x;
  if (i >= n) return;
  int mv = mask[i];
  padd[i] = mv ? -1e30f : 0.0f;
  int key = mv ? 0 : ((i & 2047) + 1);
#pragma unroll
  for (int off = 32; off; off >>= 1) key = max(key, __shfl_xor(key, off, 64));
  if ((threadIdx.x & 63) == 0) atomicMax(&kmax[i >> 11], key);  // i>>11 wave-uniform
}

// ---------------------------------------------------------------- GEMM (C = A[M,K] * B[N,K]^T)
template <int EPI>
__global__ __launch_bounds__(256) void gemm_bt(
    const unsigned short* __restrict__ A, const unsigned short* __restrict__ Bm,
    const float* __restrict__ bias, float* __restrict__ outF,
    unsigned short* __restrict__ Qb, unsigned short* __restrict__ Kb,
    unsigned short* __restrict__ Vt, int M, int N, int K) {
  __shared__ unsigned short As[128 * 32];
  __shared__ unsigned short Bs[128 * 32];
  const int tid = threadIdx.x;
  const int bm = blockIdx.x * 128;
  const int bn = blockIdx.y * 128;
  const int wave = tid >> 6, lane = tid & 63;
  const int wm = (wave >> 1) * 64, wn = (wave & 1) * 64;
  const int lr = lane & 15, lq = lane >> 4;

  f32x4 acc[4][4] = {};

  const int c0 = tid, c1 = tid + 256;
  const int rA0 = c0 >> 2, colA0 = (c0 & 3) * 8;
  const int rA1 = c1 >> 2, colA1 = (c1 & 3) * 8;

  for (int k0 = 0; k0 < K; k0 += 32) {
    __syncthreads();
    gl2lds16(A + (size_t)(bm + rA0) * K + k0 + colA0, As + c0 * 8);
    gl2lds16(A + (size_t)(bm + rA1) * K + k0 + colA1, As + c1 * 8);
    gl2lds16(Bm + (size_t)(bn + rA0) * K + k0 + colA0, Bs + c0 * 8);
    gl2lds16(Bm + (size_t)(bn + rA1) * K + k0 + colA1, Bs + c1 * 8);
    __syncthreads();
    bf16x8 af[4], bfr[4];
#pragma unroll
    for (int mi = 0; mi < 4; ++mi)
      af[mi] = *(const bf16x8*)(As + (wm + mi * 16 + lr) * 32 + lq * 8);
#pragma unroll
    for (int nj = 0; nj < 4; ++nj)
      bfr[nj] = *(const bf16x8*)(Bs + (wn + nj * 16 + lr) * 32 + lq * 8);
#pragma unroll
    for (int mi = 0; mi < 4; ++mi)
#pragma unroll
      for (int nj = 0; nj < 4; ++nj)
        acc[mi][nj] = __builtin_amdgcn_mfma_f32_16x16x32_bf16(af[mi], bfr[nj], acc[mi][nj], 0, 0, 0);
  }

#pragma unroll
  for (int mi = 0; mi < 4; ++mi) {
#pragma unroll
    for (int nj = 0; nj < 4; ++nj) {
#pragma unroll
      for (int r = 0; r < 4; ++r) {
        int m = bm + wm + mi * 16 + lq * 4 + r;
        int n = bn + wn + nj * 16 + lr;
        float v = acc[mi][nj][r] + bias[n];
        if (EPI == 0) {
          int b = m >> 11, t = m & 2047;
          int part = n >> 10, d = n & 1023;
          int h = d >> 6, hd = d & 63;
          size_t qk = ((size_t)(b * 16 + h) * 2048 + t) * 64 + hd;
          // fold softmax scale 1/sqrt(64) and log2(e) into Q
          if (part == 0)      Qb[qk] = f2bf(v * 0.18033688011112042f);
          else if (part == 1) Kb[qk] = f2bf(v);
          else                Vt[((size_t)(b * 16 + h) * 64 + hd) * 2048 + t] = f2bf(v);
        } else {
          outF[(size_t)m * N + n] = v;
        }
      }
    }
  }
}

// ---------------------------------------------------------------- flash attention
// S^T = K Q^T: C-layout (key=4*lq+r, query=lr) is directly the A-operand of
// mfma_16x16x16bf16_1k for PV — no LDS, no barriers.
// 32 q-rows per wave (2 q-tiles sharing K frags), 128-key chunks (halves the
// per-chunk epilogue count: bpermute reduces, merges, alpha broadcasts).
// 2048 waves, uniform length via pairing tile pp with 63-pp.

__device__ __forceinline__ void process_tile32(
    const unsigned short* __restrict__ Qh, const unsigned short* __restrict__ Kh,
    const unsigned short* __restrict__ Vh, const float* __restrict__ pb,
    unsigned short* __restrict__ ctxBase, int q0, int kcapR,
    int lr, int lq, int bsrc) {
  bf16x8 qf[2][2];
#pragma unroll
  for (int qt = 0; qt < 2; ++qt) {
    const unsigned short* qp = Qh + (size_t)(q0 + qt * 16 + lr) * 64 + lq * 8;
    qf[qt][0] = *(const bf16x8*)(qp);
    qf[qt][1] = *(const bf16x8*)(qp + 32);
  }
  f32x4 O[2][4] = {};
  float m[2] = {-1e30f, -1e30f}, l[2] = {0.f, 0.f};
  const bool diag = (q0 < kcapR);
  const int last = diag ? (q0 >> 7) : ((kcapR >> 7) - 1);

  for (int i = 0; i <= last; ++i) {
    const int kc = i << 7;
    f32x4 S[2][8];
    // QK^T over 128 keys (8 key-tiles of 16); both q-tiles share K frags
#pragma unroll
    for (int t = 0; t < 8; ++t) {
      const unsigned short* kp = Kh + (size_t)(kc + t * 16 + lr) * 64 + lq * 8;
      bf16x8 kf0 = *(const bf16x8*)(kp);
      bf16x8 kf1 = *(const bf16x8*)(kp + 32);
      f32x4 s0 = {}, s1 = {};
      s0 = __builtin_amdgcn_mfma_f32_16x16x32_bf16(kf0, qf[0][0], s0, 0, 0, 0);
      s0 = __builtin_amdgcn_mfma_f32_16x16x32_bf16(kf1, qf[0][1], s0, 0, 0, 0);
      s1 = __builtin_amdgcn_mfma_f32_16x16x32_bf16(kf0, qf[1][0], s1, 0, 0, 0);
      s1 = __builtin_amdgcn_mfma_f32_16x16x32_bf16(kf1, qf[1][1], s1, 0, 0, 0);
      S[0][t] = s0;
      S[1][t] = s1;
    }
    // padding addend (same for both q-tiles)
#pragma unroll
    for (int t = 0; t < 8; ++t) {
      float4 pd = *(const float4*)(pb + kc + t * 16 + 4 * lq);
#pragma unroll
      for (int qt = 0; qt < 2; ++qt) {
        S[qt][t][0] += pd.x; S[qt][t][1] += pd.y;
        S[qt][t][2] += pd.z; S[qt][t][3] += pd.w;
      }
    }
    if (diag && i == last) {
#pragma unroll
      for (int qt = 0; qt < 2; ++qt) {
        const int q = q0 + qt * 16 + lr;
#pragma unroll
        for (int t = 0; t < 8; ++t)
#pragma unroll
          for (int r = 0; r < 4; ++r) {
            int key = kc + t * 16 + 4 * lq + r;
            if (key > q) S[qt][t][r] = -1e30f;
          }
      }
    }
    // online softmax per q-tile (row = query = lr); two independent chains
    float al[2];
#pragma unroll
    for (int qt = 0; qt < 2; ++qt) {
      f32x4 vmx = S[qt][0];
#pragma unroll
      for (int t = 1; t < 8; ++t) {
        vmx[0] = fmaxf(vmx[0], S[qt][t][0]); vmx[1] = fmaxf(vmx[1], S[qt][t][1]);
        vmx[2] = fmaxf(vmx[2], S[qt][t][2]); vmx[3] = fmaxf(vmx[3], S[qt][t][3]);
      }
      float mx = fmaxf(fmaxf(vmx[0], vmx[1]), fmaxf(vmx[2], vmx[3]));
      mx = fmaxf(mx, __shfl_xor(mx, 16, 64));
      mx = fmaxf(mx, __shfl_xor(mx, 32, 64));
      float mnew = fmaxf(m[qt], mx);
      float a = __builtin_amdgcn_exp2f(m[qt] - mnew);
      m[qt] = mnew;
      f32x4 vs = {};
#pragma unroll
      for (int t = 0; t < 8; ++t) {
#pragma unroll
        for (int r = 0; r < 4; ++r) {
          float p = __builtin_amdgcn_exp2f(S[qt][t][r] - mnew);
          S[qt][t][r] = p;
          vs[r] += p;
        }
      }
      float rs = (vs[0] + vs[1]) + (vs[2] + vs[3]);
      rs += __shfl_xor(rs, 16, 64);
      rs += __shfl_xor(rs, 32, 64);
      l[qt] = l[qt] * a + rs;
      al[qt] = a;
    }
    // alpha: query=lr domain -> query=4*lq+r domain; rescale O
#pragma unroll
    for (int qt = 0; qt < 2; ++qt)
#pragma unroll
      for (int r = 0; r < 4; ++r) {
        float a = __shfl(al[qt], bsrc + r, 64);
#pragma unroll
        for (int nj = 0; nj < 4; ++nj) O[qt][nj][r] *= a;
      }
    // P cvt to bf16 A-frags (m=query=lr, k=key=4*lq+j)
    s16x4 pf[2][8];
#pragma unroll
    for (int qt = 0; qt < 2; ++qt)
#pragma unroll
      for (int t = 0; t < 8; ++t) {
        bf16x4 p4;
#pragma unroll
        for (int r = 0; r < 4; ++r) p4[r] = (__bf16)S[qt][t][r];
        pf[qt][t] = __builtin_bit_cast(s16x4, p4);
      }
    // PV: O[query=4*lq+r][hd=lr+nj*16]; V frags shared by both q-tiles
#pragma unroll
    for (int nj = 0; nj < 4; ++nj) {
      const unsigned short* vp = Vh + (size_t)(nj * 16 + lr) * 2048 + kc + 4 * lq;
#pragma unroll
      for (int t = 0; t < 8; ++t) {
        s16x4 vf = *(const s16x4*)(vp + t * 16);
        O[0][nj] = __builtin_amdgcn_mfma_f32_16x16x16bf16_1k(pf[0][t], vf, O[0][nj], 0, 0, 0);
        O[1][nj] = __builtin_amdgcn_mfma_f32_16x16x16bf16_1k(pf[1][t], vf, O[1][nj], 0, 0, 0);
      }
    }
  }

  float linv0 = 1.0f / l[0], linv1 = 1.0f / l[1];
#pragma unroll
  for (int r = 0; r < 4; ++r) {
    float li0 = __shfl(linv0, bsrc + r, 64);
    float li1 = __shfl(linv1, bsrc + r, 64);
    int q = q0 + 4 * lq + r;
    unsigned short* cp0 = ctxBase + (size_t)q * 1024 + lr;
    unsigned short* cp1 = cp0 + (size_t)16 * 1024;
#pragma unroll
    for (int nj = 0; nj < 4; ++nj) {
      cp0[nj * 16] = f2bf(O[0][nj][r] * li0);
      cp1[nj * 16] = f2bf(O[1][nj][r] * li1);
    }
  }
}

__global__ __launch_bounds__(256, 2) void flash_attn(
    const unsigned short* __restrict__ Qb, const unsigned short* __restrict__ Kb,
    const unsigned short* __restrict__ Vt, const float* __restrict__ padd,
    const int* __restrict__ kmax, unsigned short* __restrict__ ctx) {
  const int bid = blockIdx.x;      // 512 blocks
  const int pg = bid >> 6;         // 0..7
  const int bh = bid & 63;
  const int b = bh >> 4, h = bh & 15;
  const int wave = threadIdx.x >> 6, lane = threadIdx.x & 63;
  const int lr = lane & 15, lq = lane >> 4;
  const int bsrc = 20 * lq;        // lane with lr == 4*lq+r
  const int pp = pg * 4 + wave;    // 0..31: pair (63-pp, pp) of 32-row tiles

  const unsigned short* Qh = Qb + (size_t)bh * 2048 * 64;
  const unsigned short* Kh = Kb + (size_t)bh * 2048 * 64;
  const unsigned short* Vh = Vt + (size_t)bh * 64 * 2048;
  const float* pb = padd + b * 2048;
  unsigned short* ctxBase = ctx + ((size_t)b * 2048) * 1024 + h * 64;
  const int kcapR = (kmax[b] + 127) & ~127;

  process_tile32(Qh, Kh, Vh, pb, ctxBase, (63 - pp) * 32, kcapR, lr, lq, bsrc);
  process_tile32(Qh, Kh, Vh, pb, ctxBase, pp * 32, kcapR, lr, lq, bsrc);
}

// ---------------------------------------------------------------- launch
extern "C" void kernel_launch(void* const* d_in, const int* in_sizes, int n_in,
                              void* d_out, int out_size, void* d_ws, size_t ws_size,
                              hipStream_t stream) {
  const float* x    = (const float*)d_in[0];
  const float* Wqkv = (const float*)d_in[1];
  const float* bqkv = (const float*)d_in[2];
  const float* Wo   = (const float*)d_in[3];
  const float* bo   = (const float*)d_in[4];
  const int*   mask = (const int*)d_in[5];
  float* out = (float*)d_out;

  unsigned short* ws = (unsigned short*)d_ws;
  const size_t SZ_X = (size_t)8192 * 1024;  // B*T*D
  unsigned short* xb    = ws;                                   // 16 MB, reused as ctx
  unsigned short* WqkvT = xb + SZ_X;                            // 6 MB
  unsigned short* WoT   = WqkvT + (size_t)3072 * 1024;          // 2 MB
  unsigned short* Qb    = WoT + (size_t)1024 * 1024;            // 16 MB
  unsigned short* Kb    = Qb + SZ_X;                            // 16 MB
  unsigned short* Vt    = Kb + SZ_X;                            // 16 MB
  float*          padd  = (float*)(Vt + SZ_X);                  // 32 KB
  int*            kmax  = (int*)(padd + 8192);                  // 16 B
  unsigned short* ctx   = xb;  // xb dead after GEMM1

  hipMemsetAsync(kmax, 0, 4 * sizeof(int), stream);
  cast_f32_bf16<<<8192, 256, 0, stream>>>(x, xb, (int)SZ_X);
  transpose_cast<<<dim3(96, 32), dim3(32, 8), 0, stream>>>(Wqkv, WqkvT, 1024, 3072);
  transpose_cast<<<dim3(32, 32), dim3(32, 8), 0, stream>>>(Wo, WoT, 1024, 1024);
  prep_pad<<<32, 256, 0, stream>>>(mask, padd, kmax, 8192);
  gemm_bt<0><<<dim3(64, 24), 256, 0, stream>>>(xb, WqkvT, bqkv, nullptr, Qb, Kb, Vt,
                                               8192, 3072, 1024);
  flash_attn<<<512, 256, 0, stream>>>(Qb, Kb, Vt, padd, kmax, ctx);
  gemm_bt<1><<<dim3(64, 8), 256, 0, stream>>>(ctx, WoT, bo, out, nullptr, nullptr, nullptr,
                                              8192, 1024, 1024);
}